// Round 17
// baseline (96.184 us; speedup 1.0000x reference)
//
#include <hip/hip_runtime.h>

// Linear (kernelized) attention, N=8 L=S=8192 H=8 D=32, fp32.
// out = (Q'·(K'^T V)) / (Q'·Ksum + eps), Q'/K' = elu(x)+1.
// The /v_length and *v_length in the reference cancel exactly (2^13).

constexpr int N_ = 8, L_ = 8192, S_ = 8192, H_ = 8, D_ = 32;
constexpr int NH = N_ * H_;                  // 64 (n,h) pairs
constexpr int SPLIT = 32;                    // S-chunks per (n,h) -> 2048 blocks
constexpr int CS = S_ / SPLIT;               // 256 rows per block
constexpr int PART_STRIDE = D_ * D_ + D_;    // 1024 KV + 32 Ksum = 1056
constexpr int LCH = 256;                     // L-chunk per phase-2 block
constexpr float EPS_ = 1e-6f;
constexpr int HD = H_ * D_;                  // 256

typedef float f32x4 __attribute__((ext_vector_type(4)));
typedef float f32x2 __attribute__((ext_vector_type(2)));

__device__ __forceinline__ float fmap(float x) {
    // elu(x)+1  (alpha=1): x>0 ? x+1 : exp(x)
    return x > 0.0f ? x + 1.0f : __expf(x);
}

// nontemporal 16B load: bypasses L2/L3 (nt). K/V are single-use streams.
__device__ __forceinline__ f32x4 ntl(const float* p) {
    return __builtin_nontemporal_load(reinterpret_cast<const f32x4*>(p));
}

// ---------------- phase 1: partial KV (D x D) + Ksum per (n,h,s-chunk) -----
// Round-13..16 version verbatim (NT loads; 46.5us = 2.88TB/s read, ~90% of
// the best read rate ever demonstrated on this part).
__global__ __launch_bounds__(256, 4) void lin_attn_phase1(
        const float* __restrict__ Kg, const float* __restrict__ Vg,
        float* __restrict__ part) {
    const int blk = blockIdx.x;
    const int nh = blk / SPLIT;
    const int sc = blk % SPLIT;
    const int n = nh / H_, h = nh % H_;
    const int t = threadIdx.x;
    const int w = t >> 6;             // wave 0..3
    const int j = t & 63;             // lane
    const int half = j >> 5;          // 0/1: which of the 2 rows this beat
    const int jj = j & 31;
    const int d0 = (jj & 7) << 2;     // K quad: d0..d0+3
    const int v0 = (jj >> 3) << 3;    // V oct:  v0..v0+7

    __shared__ __align__(16) float red[4][1024];
    __shared__ __align__(16) float ksum_red[4][32];

    float acc[4][8];
    #pragma unroll
    for (int a = 0; a < 4; ++a)
        #pragma unroll
        for (int b = 0; b < 8; ++b) acc[a][b] = 0.0f;
    float kp[4] = {0.f, 0.f, 0.f, 0.f};

    const size_t base = (size_t)n * S_ * H_ * D_ + (size_t)h * D_;
    const int s0 = sc * CS;
    const float* kr = Kg + base + (size_t)(s0 + (w << 1) + half) * HD + d0;
    const float* vr = Vg + base + (size_t)(s0 + (w << 1) + half) * HD + v0;
    constexpr int STRIDE = 8 * HD;    // 8 rows per beat-step

#define BEAT(kq, va, vb) do {                                                  \
        float kd[4];                                                           \
        kd[0] = fmap((kq).x); kd[1] = fmap((kq).y);                            \
        kd[2] = fmap((kq).z); kd[3] = fmap((kq).w);                            \
        kp[0] += kd[0]; kp[1] += kd[1]; kp[2] += kd[2]; kp[3] += kd[3];        \
        const float vs[8] = {(va).x, (va).y, (va).z, (va).w,                   \
                             (vb).x, (vb).y, (vb).z, (vb).w};                  \
        _Pragma("unroll")                                                      \
        for (int a = 0; a < 4; ++a)                                            \
            _Pragma("unroll")                                                  \
            for (int bb = 0; bb < 8; ++bb)                                     \
                acc[a][bb] += kd[a] * vs[bb];                                  \
    } while (0)

    // prologue: beats 0 and 1 in flight (2-deep: 6 loads/wave outstanding)
    f32x4 kqA = ntl(kr);
    f32x4 vaA = ntl(vr);
    f32x4 vbA = ntl(vr + 4);
    f32x4 kqB = ntl(kr + STRIDE);
    f32x4 vaB = ntl(vr + STRIDE);
    f32x4 vbB = ntl(vr + STRIDE + 4);
    kr += 2 * STRIDE; vr += 2 * STRIDE;

    #pragma unroll 1
    for (int b = 0; b < (CS / 8 - 2) / 2; ++b) {   // 15 iters, 2 beats each
        f32x4 kqn = ntl(kr);
        f32x4 van = ntl(vr);
        f32x4 vbn = ntl(vr + 4);
        BEAT(kqA, vaA, vbA);
        kqA = kqn; vaA = van; vbA = vbn;
        kqn = ntl(kr + STRIDE);
        van = ntl(vr + STRIDE);
        vbn = ntl(vr + STRIDE + 4);
        BEAT(kqB, vaB, vbB);
        kqB = kqn; vaB = van; vbB = vbn;
        kr += 2 * STRIDE; vr += 2 * STRIDE;
    }
    BEAT(kqA, vaA, vbA);
    BEAT(kqB, vaB, vbB);
#undef BEAT

    // ---- cross-half (rows split even/odd) reduce, in-register ----
    #pragma unroll
    for (int a = 0; a < 4; ++a)
        #pragma unroll
        for (int bb = 0; bb < 8; ++bb)
            acc[a][bb] += __shfl_xor(acc[a][bb], 32);
    #pragma unroll
    for (int a = 0; a < 4; ++a) kp[a] += __shfl_xor(kp[a], 32);

    // ---- per-wave partial to LDS (lanes 0..31 hold the full sums) ----
    if (j < 32) {
        #pragma unroll
        for (int a = 0; a < 4; ++a) {
            *reinterpret_cast<float4*>(&red[w][(d0 + a) * D_ + v0]) =
                make_float4(acc[a][0], acc[a][1], acc[a][2], acc[a][3]);
            *reinterpret_cast<float4*>(&red[w][(d0 + a) * D_ + v0 + 4]) =
                make_float4(acc[a][4], acc[a][5], acc[a][6], acc[a][7]);
        }
        if (j < 8)   // kp duplicated across v-groups; one writer per d-quad
            *reinterpret_cast<float4*>(&ksum_red[w][j << 2]) =
                make_float4(kp[0], kp[1], kp[2], kp[3]);
    }
    __syncthreads();

    // ---- block-level reduce over the 4 waves, write partial ----
    float* P = part + ((size_t)sc * NH + nh) * PART_STRIDE;
    const int i4 = t << 2;            // 0,4,...,1020
    float4 s = make_float4(0.f, 0.f, 0.f, 0.f);
    #pragma unroll
    for (int w2 = 0; w2 < 4; ++w2) {
        const float4 rr = *reinterpret_cast<const float4*>(&red[w2][i4]);
        s.x += rr.x; s.y += rr.y; s.z += rr.z; s.w += rr.w;
    }
    *reinterpret_cast<float4*>(&P[i4]) = s;
    if (t < D_) {
        float ks = 0.f;
        #pragma unroll
        for (int w2 = 0; w2 < 4; ++w2) ks += ksum_red[w2][t];
        P[D_ * D_ + t] = ks;
    }
}

// ---------------- reduce the SPLIT partials -------------------------------
__global__ __launch_bounds__(256) void lin_attn_reduce(
        const float* __restrict__ part, float* __restrict__ red) {
    const int i = blockIdx.x * 256 + threadIdx.x;
    if (i >= NH * PART_STRIDE) return;
    float s = 0.0f;
    #pragma unroll 8
    for (int sc = 0; sc < SPLIT; ++sc)
        s += part[(size_t)sc * (NH * PART_STRIDE) + i];
    red[i] = s;
}

// ---------------- phase 2: out = (Q'.KV) * zinv, zinv = 1/(Q'.Ksum+eps) ----
// TRUE register pinning: r14-r16's "register" kv tables were silently
// rematerialized (VGPR_Count 36/80 << table size) -> inner loop re-read the
// KV table from LDS/cache every step (~25-30us of LDS issue, the measured
// phase2 floor). Fix: load kv once from global red (270KB, L2-resident) and
// pin every value with empty inline asm (opaque producer -> cannot be
// rematerialized; spill would show in WRITE_SIZE). Mapping r15: thread owns
// 2 columns x rows {rg, rg+16}; one wave instr serves 4 rows; Qt stride 34
// keeps those conflict-free. launch_bounds(256,4): cap 128 VGPR, est ~105.
__global__ __launch_bounds__(256, 4) void lin_attn_phase2(
        const float* __restrict__ Qg, const float* __restrict__ red,
        float* __restrict__ outg) {
    constexpr int QTS = 32;           // Q tile rows
    constexpr int QSTR = 34;          // padded Qt row stride (floats)
    constexpr int NLC = L_ / LCH;     // 32
    const int nh  = blockIdx.x / NLC;
    const int lcb = blockIdx.x % NLC;
    const int n = nh / H_, h = nh % H_;
    const int t = threadIdx.x;
    const int vp = t & 15;            // v-pair: outputs 2vp, 2vp+1
    const int rg = t >> 4;            // 0..15: rows rg, rg+16
    const int r  = t >> 3;            // staging row 0..31
    const int c  = (t & 7) << 2;      // staging col

    __shared__ __align__(16) float Qt[QTS][QSTR];
    __shared__ float zinv_sh[QTS];

    // ---- kv column pair, loaded once and PINNED in VGPRs ----
    const float* W = red + (size_t)nh * PART_STRIDE;
    float kvx[D_], kvy[D_];
    #pragma unroll
    for (int d = 0; d < D_; ++d) {
        const f32x2 p = *reinterpret_cast<const f32x2*>(W + d * D_ + (vp << 1));
        float a = p.x, b = p.y;
        asm volatile("" : "+v"(a), "+v"(b));   // opaque: no rematerialization
        kvx[d] = a; kvy[d] = b;
    }
    const float4 ksq = *reinterpret_cast<const float4*>(W + D_ * D_ + c);

    const size_t base = (size_t)n * L_ * H_ * D_ + (size_t)h * D_;
    const int l0 = lcb * LCH;
    const float* qp = Qg + base + (size_t)(l0 + r) * HD + c;

    float4 q4 = *reinterpret_cast<const float4*>(qp);    // preload tile 0
    #pragma unroll 1
    for (int step = 0; step < LCH; step += QTS) {
        __syncthreads();   // previous Qt/zinv fully consumed
        float4 qf;
        qf.x = fmap(q4.x); qf.y = fmap(q4.y);
        qf.z = fmap(q4.z); qf.w = fmap(q4.w);
        *reinterpret_cast<float4*>(&Qt[r][c]) = qf;
        // per-row z: dot(q-quad, ksum-quad), folded across the 8 staging lanes
        float zp = qf.x * ksq.x + qf.y * ksq.y + qf.z * ksq.z + qf.w * ksq.w;
        zp += __shfl_xor(zp, 1);
        zp += __shfl_xor(zp, 2);
        zp += __shfl_xor(zp, 4);
        if ((t & 7) == 0) zinv_sh[r] = 1.0f / (zp + EPS_);
        __syncthreads();
        if (step + QTS < LCH)          // issue next tile's load NOW
            q4 = *reinterpret_cast<const float4*>(
                qp + (size_t)(step + QTS) * HD);
        #pragma unroll
        for (int rr = 0; rr < 2; ++rr) {
            const int row = rg + (rr << 4);
            float a0 = 0.0f, a1 = 0.0f;
            #pragma unroll
            for (int d2 = 0; d2 < 16; ++d2) {   // 4-addr b64 broadcast reads
                const f32x2 q = *reinterpret_cast<const f32x2*>(&Qt[row][d2 << 1]);
                a0 += q.x * kvx[(d2 << 1)] + q.y * kvx[(d2 << 1) + 1];
                a1 += q.x * kvy[(d2 << 1)] + q.y * kvy[(d2 << 1) + 1];
            }
            const float zi = zinv_sh[row];
            f32x2 o; o.x = a0 * zi; o.y = a1 * zi;
            __builtin_nontemporal_store(o, reinterpret_cast<f32x2*>(
                outg + base + (size_t)(l0 + step + row) * HD + (vp << 1)));
        }
    }
}

extern "C" void kernel_launch(void* const* d_in, const int* in_sizes, int n_in,
                              void* d_out, int out_size, void* d_ws, size_t ws_size,
                              hipStream_t stream) {
    const float* Q = (const float*)d_in[0];
    const float* K = (const float*)d_in[1];
    const float* V = (const float*)d_in[2];
    float* out  = (float*)d_out;
    float* part = (float*)d_ws;                                   // 32*64*1056 f32
    float* red  = part + (size_t)SPLIT * NH * PART_STRIDE;        // 64*1056 f32

    lin_attn_phase1<<<NH * SPLIT, 256, 0, stream>>>(K, V, part);
    lin_attn_reduce<<<(NH * PART_STRIDE + 255) / 256, 256, 0, stream>>>(part, red);
    lin_attn_phase2<<<NH * (L_ / LCH), 256, 0, stream>>>(Q, red, out);
}

// Round 18
// 79.577 us; speedup vs baseline: 1.2087x; 1.2087x over previous
//
#include <hip/hip_runtime.h>

// Linear (kernelized) attention, N=8 L=S=8192 H=8 D=32, fp32.
// out = (Q'·(K'^T V)) / (Q'·Ksum + eps), Q'/K' = elu(x)+1.
// The /v_length and *v_length in the reference cancel exactly (2^13).
//
// FINAL (round-16 revert): best measured total 79.39us.
//  - phase1: NT-load streaming, 2.88TB/s read (~90% of the best read rate
//    demonstrated on this part by any kernel incl. pure-copy patterns).
//  - phase2: LDS-broadcast GEMV, 8 lanes/row, f32x4 accumulate, NT stores.
//    Register-pinning the KV table was tried 3 ways (r14/r16 implicit,
//    r17 asm-pin) — allocator always demotes it; LDS re-read is the floor.

constexpr int N_ = 8, L_ = 8192, S_ = 8192, H_ = 8, D_ = 32;
constexpr int NH = N_ * H_;                  // 64 (n,h) pairs
constexpr int SPLIT = 32;                    // S-chunks per (n,h) -> 2048 blocks
constexpr int CS = S_ / SPLIT;               // 256 rows per block
constexpr int PART_STRIDE = D_ * D_ + D_;    // 1024 KV + 32 Ksum = 1056
constexpr int LCH = 256;                     // L-chunk per phase-2 block
constexpr float EPS_ = 1e-6f;
constexpr int HD = H_ * D_;                  // 256

typedef float f32x4 __attribute__((ext_vector_type(4)));
typedef float f32x2 __attribute__((ext_vector_type(2)));

__device__ __forceinline__ float fmap(float x) {
    // elu(x)+1  (alpha=1): x>0 ? x+1 : exp(x)
    return x > 0.0f ? x + 1.0f : __expf(x);
}

// nontemporal 16B load: bypasses L2/L3 (nt). K/V are single-use streams.
__device__ __forceinline__ f32x4 ntl(const float* p) {
    return __builtin_nontemporal_load(reinterpret_cast<const f32x4*>(p));
}

// ---------------- phase 1: partial KV (D x D) + Ksum per (n,h,s-chunk) -----
__global__ __launch_bounds__(256, 4) void lin_attn_phase1(
        const float* __restrict__ Kg, const float* __restrict__ Vg,
        float* __restrict__ part) {
    const int blk = blockIdx.x;
    const int nh = blk / SPLIT;
    const int sc = blk % SPLIT;
    const int n = nh / H_, h = nh % H_;
    const int t = threadIdx.x;
    const int w = t >> 6;             // wave 0..3
    const int j = t & 63;             // lane
    const int half = j >> 5;          // 0/1: which of the 2 rows this beat
    const int jj = j & 31;
    const int d0 = (jj & 7) << 2;     // K quad: d0..d0+3
    const int v0 = (jj >> 3) << 3;    // V oct:  v0..v0+7

    __shared__ __align__(16) float red[4][1024];
    __shared__ __align__(16) float ksum_red[4][32];

    float acc[4][8];
    #pragma unroll
    for (int a = 0; a < 4; ++a)
        #pragma unroll
        for (int b = 0; b < 8; ++b) acc[a][b] = 0.0f;
    float kp[4] = {0.f, 0.f, 0.f, 0.f};

    const size_t base = (size_t)n * S_ * H_ * D_ + (size_t)h * D_;
    const int s0 = sc * CS;
    const float* kr = Kg + base + (size_t)(s0 + (w << 1) + half) * HD + d0;
    const float* vr = Vg + base + (size_t)(s0 + (w << 1) + half) * HD + v0;
    constexpr int STRIDE = 8 * HD;    // 8 rows per beat-step

#define BEAT(kq, va, vb) do {                                                  \
        float kd[4];                                                           \
        kd[0] = fmap((kq).x); kd[1] = fmap((kq).y);                            \
        kd[2] = fmap((kq).z); kd[3] = fmap((kq).w);                            \
        kp[0] += kd[0]; kp[1] += kd[1]; kp[2] += kd[2]; kp[3] += kd[3];        \
        const float vs[8] = {(va).x, (va).y, (va).z, (va).w,                   \
                             (vb).x, (vb).y, (vb).z, (vb).w};                  \
        _Pragma("unroll")                                                      \
        for (int a = 0; a < 4; ++a)                                            \
            _Pragma("unroll")                                                  \
            for (int bb = 0; bb < 8; ++bb)                                     \
                acc[a][bb] += kd[a] * vs[bb];                                  \
    } while (0)

    // prologue: beats 0 and 1 in flight (2-deep: 6 loads/wave outstanding)
    f32x4 kqA = ntl(kr);
    f32x4 vaA = ntl(vr);
    f32x4 vbA = ntl(vr + 4);
    f32x4 kqB = ntl(kr + STRIDE);
    f32x4 vaB = ntl(vr + STRIDE);
    f32x4 vbB = ntl(vr + STRIDE + 4);
    kr += 2 * STRIDE; vr += 2 * STRIDE;

    #pragma unroll 1
    for (int b = 0; b < (CS / 8 - 2) / 2; ++b) {   // 15 iters, 2 beats each
        f32x4 kqn = ntl(kr);
        f32x4 van = ntl(vr);
        f32x4 vbn = ntl(vr + 4);
        BEAT(kqA, vaA, vbA);
        kqA = kqn; vaA = van; vbA = vbn;
        kqn = ntl(kr + STRIDE);
        van = ntl(vr + STRIDE);
        vbn = ntl(vr + STRIDE + 4);
        BEAT(kqB, vaB, vbB);
        kqB = kqn; vaB = van; vbB = vbn;
        kr += 2 * STRIDE; vr += 2 * STRIDE;
    }
    BEAT(kqA, vaA, vbA);
    BEAT(kqB, vaB, vbB);
#undef BEAT

    // ---- cross-half (rows split even/odd) reduce, in-register ----
    #pragma unroll
    for (int a = 0; a < 4; ++a)
        #pragma unroll
        for (int bb = 0; bb < 8; ++bb)
            acc[a][bb] += __shfl_xor(acc[a][bb], 32);
    #pragma unroll
    for (int a = 0; a < 4; ++a) kp[a] += __shfl_xor(kp[a], 32);

    // ---- per-wave partial to LDS (lanes 0..31 hold the full sums) ----
    if (j < 32) {
        #pragma unroll
        for (int a = 0; a < 4; ++a) {
            *reinterpret_cast<float4*>(&red[w][(d0 + a) * D_ + v0]) =
                make_float4(acc[a][0], acc[a][1], acc[a][2], acc[a][3]);
            *reinterpret_cast<float4*>(&red[w][(d0 + a) * D_ + v0 + 4]) =
                make_float4(acc[a][4], acc[a][5], acc[a][6], acc[a][7]);
        }
        if (j < 8)   // kp duplicated across v-groups; one writer per d-quad
            *reinterpret_cast<float4*>(&ksum_red[w][j << 2]) =
                make_float4(kp[0], kp[1], kp[2], kp[3]);
    }
    __syncthreads();

    // ---- block-level reduce over the 4 waves, write partial ----
    float* P = part + ((size_t)sc * NH + nh) * PART_STRIDE;
    const int i4 = t << 2;            // 0,4,...,1020
    float4 s = make_float4(0.f, 0.f, 0.f, 0.f);
    #pragma unroll
    for (int w2 = 0; w2 < 4; ++w2) {
        const float4 rr = *reinterpret_cast<const float4*>(&red[w2][i4]);
        s.x += rr.x; s.y += rr.y; s.z += rr.z; s.w += rr.w;
    }
    *reinterpret_cast<float4*>(&P[i4]) = s;
    if (t < D_) {
        float ks = 0.f;
        #pragma unroll
        for (int w2 = 0; w2 < 4; ++w2) ks += ksum_red[w2][t];
        P[D_ * D_ + t] = ks;
    }
}

// ---------------- reduce the SPLIT partials -------------------------------
__global__ __launch_bounds__(256) void lin_attn_reduce(
        const float* __restrict__ part, float* __restrict__ red) {
    const int i = blockIdx.x * 256 + threadIdx.x;
    if (i >= NH * PART_STRIDE) return;
    float s = 0.0f;
    #pragma unroll 8
    for (int sc = 0; sc < SPLIT; ++sc)
        s += part[(size_t)sc * (NH * PART_STRIDE) + i];
    red[i] = s;
}

// ---------------- phase 2: out = (Q'.KV) * zinv, zinv = 1/(Q'.Ksum+eps) ----
// Round-16 version: thread covers 4 output cols (f32x4 accumulate), 8 lanes
// per row -> one wave LDS instr serves 8 rows; staging mapping doubles as
// compute mapping; coalesced NT f32x4 stores; Qt stride 34 for bank spread.
__global__ __launch_bounds__(256, 2) void lin_attn_phase2(
        const float* __restrict__ Qg, const float* __restrict__ red,
        float* __restrict__ outg) {
    constexpr int QTS = 32;           // Q tile rows
    constexpr int QSTR = 34;          // padded Qt row stride (floats)
    constexpr int NLC = L_ / LCH;     // 32
    const int nh  = blockIdx.x / NLC;
    const int lcb = blockIdx.x % NLC;
    const int n = nh / H_, h = nh % H_;
    const int t = threadIdx.x;
    const int r  = t >> 3;            // staging & compute row 0..31
    const int c  = (t & 7) << 2;      // staging & output col quad

    __shared__ __align__(16) float KVs[PART_STRIDE];   // KV table + Ksum
    __shared__ __align__(16) float Qt[QTS][QSTR];
    __shared__ float zinv_sh[QTS];

    // ---- stage KV table (1056 floats) once per block, coalesced ----
    {
        const float* W = red + (size_t)nh * PART_STRIDE;
        *reinterpret_cast<float4*>(&KVs[t << 2]) =
            *reinterpret_cast<const float4*>(W + (t << 2));        // 1024 KV
        if (t < 8)
            *reinterpret_cast<float4*>(&KVs[1024 + (t << 2)]) =
                *reinterpret_cast<const float4*>(W + 1024 + (t << 2)); // Ksum
    }
    __syncthreads();

    // thread-private 4-column kv slice (allocator may serve from LDS;
    // measured best among all variants)
    f32x4 kv[D_];
    #pragma unroll
    for (int d = 0; d < D_; ++d)
        kv[d] = *reinterpret_cast<const f32x4*>(&KVs[d * D_ + c]);
    const float4 ksq = *reinterpret_cast<const float4*>(&KVs[D_ * D_ + c]);

    const size_t base = (size_t)n * L_ * H_ * D_ + (size_t)h * D_;
    const int l0 = lcb * LCH;
    const float* qp = Qg + base + (size_t)(l0 + r) * HD + c;

    float4 q4 = *reinterpret_cast<const float4*>(qp);    // preload tile 0
    #pragma unroll 1
    for (int step = 0; step < LCH; step += QTS) {
        __syncthreads();   // previous Qt/zinv fully consumed
        float4 qf;
        qf.x = fmap(q4.x); qf.y = fmap(q4.y);
        qf.z = fmap(q4.z); qf.w = fmap(q4.w);
        *reinterpret_cast<float4*>(&Qt[r][c]) = qf;
        // per-row z: dot(q-quad, ksum-quad), folded across the 8 staging lanes
        float zp = qf.x * ksq.x + qf.y * ksq.y + qf.z * ksq.z + qf.w * ksq.w;
        zp += __shfl_xor(zp, 1);
        zp += __shfl_xor(zp, 2);
        zp += __shfl_xor(zp, 4);
        if ((t & 7) == 0) zinv_sh[r] = 1.0f / (zp + EPS_);
        __syncthreads();
        if (step + QTS < LCH)          // issue next tile's load NOW
            q4 = *reinterpret_cast<const float4*>(
                qp + (size_t)(step + QTS) * HD);
        f32x4 a = {0.f, 0.f, 0.f, 0.f};
        #pragma unroll
        for (int d2 = 0; d2 < 16; ++d2) {   // 8-row-group b64 broadcast reads
            const f32x2 q = *reinterpret_cast<const f32x2*>(&Qt[r][d2 << 1]);
            a += q.x * kv[(d2 << 1)];
            a += q.y * kv[(d2 << 1) + 1];
        }
        const float zi = zinv_sh[r];
        f32x4 o = a * zi;
        __builtin_nontemporal_store(o, reinterpret_cast<f32x4*>(
            outg + base + (size_t)(l0 + step + r) * HD + c));
    }
}

extern "C" void kernel_launch(void* const* d_in, const int* in_sizes, int n_in,
                              void* d_out, int out_size, void* d_ws, size_t ws_size,
                              hipStream_t stream) {
    const float* Q = (const float*)d_in[0];
    const float* K = (const float*)d_in[1];
    const float* V = (const float*)d_in[2];
    float* out  = (float*)d_out;
    float* part = (float*)d_ws;                                   // 32*64*1056 f32
    float* red  = part + (size_t)SPLIT * NH * PART_STRIDE;        // 64*1056 f32

    lin_attn_phase1<<<NH * SPLIT, 256, 0, stream>>>(K, V, part);
    lin_attn_reduce<<<(NH * PART_STRIDE + 255) / 256, 256, 0, stream>>>(part, red);
    lin_attn_phase2<<<NH * (L_ / LCH), 256, 0, stream>>>(Q, red, out);
}